// Round 3
// baseline (220.330 us; speedup 1.0000x reference)
//
#include <hip/hip_runtime.h>
#include <stdint.h>

#define B_SZ 4
#define T_SEQ 2048
#define C_DIM 1024
#define NH 16
#define DH 64
#define CTX 256

#define AS_G const __attribute__((address_space(1))) void*
#define AS_L __attribute__((address_space(3))) void*

typedef __attribute__((ext_vector_type(8))) short bf16x8;
typedef __attribute__((ext_vector_type(8))) unsigned short u16x8;
typedef __attribute__((ext_vector_type(4))) float f32x4;

__device__ __forceinline__ float bf2f(unsigned short u) {
  unsigned int x = ((unsigned int)u) << 16;
  return __builtin_bit_cast(float, x);
}
__device__ __forceinline__ unsigned short f2bf(float f) {
  unsigned int u = __builtin_bit_cast(unsigned int, f);
  u = (u + 0x7FFFu + ((u >> 16) & 1u)) >> 16;  // RNE; inputs are NaN/inf-free
  return (unsigned short)u;
}

// ---------------- conversion kernels ----------------

__global__ void cvt_f32_bf16(const float* __restrict__ in,
                             unsigned short* __restrict__ out, int n8) {
  int i = blockIdx.x * blockDim.x + threadIdx.x;
  int stride = gridDim.x * blockDim.x;
  for (; i < n8; i += stride) {
    float4 a = ((const float4*)in)[2 * (size_t)i];
    float4 b = ((const float4*)in)[2 * (size_t)i + 1];
    u16x8 r;
    r[0] = f2bf(a.x); r[1] = f2bf(a.y); r[2] = f2bf(a.z); r[3] = f2bf(a.w);
    r[4] = f2bf(b.x); r[5] = f2bf(b.y); r[6] = f2bf(b.z); r[7] = f2bf(b.w);
    *(u16x8*)(out + 8 * (size_t)i) = r;
  }
}

// W[R][CC] f32 -> Wt[CC][R] bf16
__global__ void transpose_cvt(const float* __restrict__ W,
                              unsigned short* __restrict__ Wt, int R, int CC) {
  __shared__ float tile[32][33];
  int ct = blockIdx.x, rt = blockIdx.y;
  int tx = threadIdx.x & 31, ty = threadIdx.x >> 5;
#pragma unroll
  for (int i = 0; i < 4; ++i) {
    int r = ty + i * 8;
    tile[r][tx] = W[(size_t)(rt * 32 + r) * CC + ct * 32 + tx];
  }
  __syncthreads();
#pragma unroll
  for (int i = 0; i < 4; ++i) {
    int r = ty + i * 8;
    Wt[(size_t)(ct * 32 + r) * R + rt * 32 + tx] = f2bf(tile[tx][r]);
  }
}

// V [B,H,T,D] -> VT [B,H,D,T]  (both sides coalesced)
__global__ void v_transpose(const unsigned short* __restrict__ Vb,
                            unsigned short* __restrict__ VT) {
  int idx = blockIdx.x * 256 + threadIdx.x;  // over B*H*T
  int bh = idx >> 11;
  int t = idx & (T_SEQ - 1);
  const unsigned short* src = Vb + ((size_t)bh * T_SEQ + t) * DH;
  unsigned short* dst = VT + (size_t)bh * DH * T_SEQ + t;
#pragma unroll
  for (int d0 = 0; d0 < DH; d0 += 8) {
    u16x8 v = *(const u16x8*)(src + d0);
#pragma unroll
    for (int e = 0; e < 8; ++e) dst[(size_t)(d0 + e) * T_SEQ] = v[e];
  }
}

// ---------------- bf16 MFMA GEMM, B^T layout ----------------
// C[M,N] = A[M,K] * Bt[N,K]^T + bias.  mode 0: fp32 out. mode 1: scatter QKV.
// m97 structure: global_load_lds width=16, LINEAR [128][64] LDS (no swizzle —
// gload_lds dest is wave-uniform base + lane*16, can't scatter; 16-way
// ds_read conflict is tolerated per m97/m98 at this 2-barrier structure).
#define BM 128
#define BN 128
#define BK 64

__global__ __launch_bounds__(256) void gemm_bt(
    const unsigned short* __restrict__ A, const unsigned short* __restrict__ Bt,
    const float* __restrict__ bias, int N, int K, int mode,
    float* __restrict__ outF, unsigned short* __restrict__ Qb,
    unsigned short* __restrict__ Kb, unsigned short* __restrict__ Vb) {
  __shared__ unsigned short As[BM * BK];
  __shared__ unsigned short Bs[BN * BK];
  const int tid = threadIdx.x;
  const int lane = tid & 63;
  const int w = tid >> 6;
  const int wm = w >> 1, wn = w & 1;
  const int m0 = blockIdx.y * BM, n0 = blockIdx.x * BN;

  // staging: lane l of group r8 covers LDS bytes r8*1024 + l*16
  //   -> row r8*8 + (l>>3), 16B-chunk (l&7); global src matches.
  const int srow = lane >> 3;
  const int sch = lane & 7;

  f32x4 acc[4][4];
#pragma unroll
  for (int mi = 0; mi < 4; ++mi)
#pragma unroll
    for (int ni = 0; ni < 4; ++ni) acc[mi][ni] = (f32x4){0.f, 0.f, 0.f, 0.f};

  for (int k0 = 0; k0 < K; k0 += BK) {
#pragma unroll
    for (int i = 0; i < 4; ++i) {
      int r8 = w * 4 + i;  // 8-row group 0..15
      int row = r8 * 8 + srow;
      __builtin_amdgcn_global_load_lds(
          (AS_G)&A[(size_t)(m0 + row) * K + k0 + sch * 8],
          (AS_L)((__attribute__((address_space(3))) unsigned short*)As + r8 * 512),
          16, 0, 0);
      __builtin_amdgcn_global_load_lds(
          (AS_G)&Bt[(size_t)(n0 + row) * K + k0 + sch * 8],
          (AS_L)((__attribute__((address_space(3))) unsigned short*)Bs + r8 * 512),
          16, 0, 0);
    }
    __syncthreads();
#pragma unroll
    for (int ks = 0; ks < 2; ++ks) {
      bf16x8 av[4], bv[4];
      const int colc = (ks << 2) + (lane >> 4);  // 16B chunk index in row
#pragma unroll
      for (int mi = 0; mi < 4; ++mi) {
        int row = wm * 64 + mi * 16 + (lane & 15);
        av[mi] = *(const bf16x8*)&As[row * BK + (colc << 3)];
      }
#pragma unroll
      for (int ni = 0; ni < 4; ++ni) {
        int row = wn * 64 + ni * 16 + (lane & 15);
        bv[ni] = *(const bf16x8*)&Bs[row * BK + (colc << 3)];
      }
#pragma unroll
      for (int mi = 0; mi < 4; ++mi)
#pragma unroll
        for (int ni = 0; ni < 4; ++ni)
          acc[mi][ni] = __builtin_amdgcn_mfma_f32_16x16x32_bf16(
              av[mi], bv[ni], acc[mi][ni], 0, 0, 0);
    }
    __syncthreads();
  }

  // epilogue: C/D layout col=lane&15, row=(lane>>4)*4+j  (m89/m91 verified)
#pragma unroll
  for (int mi = 0; mi < 4; ++mi) {
#pragma unroll
    for (int ni = 0; ni < 4; ++ni) {
      int gn = n0 + wn * 64 + ni * 16 + (lane & 15);
      float bb = bias[gn];
#pragma unroll
      for (int j = 0; j < 4; ++j) {
        int gm = m0 + wm * 64 + mi * 16 + ((lane >> 4) << 2) + j;
        float v = acc[mi][ni][j] + bb;
        if (mode == 0) {
          outF[(size_t)gm * N + gn] = v;
        } else {
          int sec = gn >> 10, cc = gn & 1023;
          int h = cc >> 6, d = cc & 63;
          int b = gm >> 11, t = gm & 2047;
          size_t dst = (((size_t)(b * NH + h) * T_SEQ) + t) * DH + d;
          float sv = (sec == 0) ? v * 0.125f : v;  // pre-scale Q by 1/sqrt(D)
          unsigned short hv = f2bf(sv);
          if (sec == 0) Qb[dst] = hv;
          else if (sec == 1) Kb[dst] = hv;
          else Vb[dst] = hv;
        }
      }
    }
  }
}

// ---------------- banded causal flash attention (MFMA) ----------------
// one wave per 16-row Q-tile; 4 waves/block; no inter-wave sync needed.
__global__ __launch_bounds__(256) void attn_mfma(
    const unsigned short* __restrict__ Qb,  // [B,H,T,D] (pre-scaled)
    const unsigned short* __restrict__ Kb,  // [B,H,T,D]
    const unsigned short* __restrict__ VT,  // [B,H,D,T]
    unsigned short* __restrict__ Ab) {      // [B,T,C]
  __shared__ unsigned short Pb[4][16][40];  // padded: row stride 80B
  const int wid = threadIdx.x >> 6, lane = threadIdx.x & 63;
  const int lo = lane & 15, hi = lane >> 4;
  const int bh = blockIdx.x >> 5;                       // 32 blocks per (b,h)
  const int t0 = ((blockIdx.x & 31) * 4 + wid) * 16;    // q-tile start
  const int b = bh >> 4, h = bh & 15;
  const size_t base = (size_t)bh * (T_SEQ * DH);

  // Q A-frags (row = lo, k = hi*8+e)
  const unsigned short* qp = Qb + base + (size_t)(t0 + lo) * DH + hi * 8;
  bf16x8 qa0 = *(const bf16x8*)qp;
  bf16x8 qa1 = *(const bf16x8*)(qp + 32);

  f32x4 O[4];
#pragma unroll
  for (int f = 0; f < 4; ++f) O[f] = (f32x4){0.f, 0.f, 0.f, 0.f};
  float m[4], l[4];
#pragma unroll
  for (int j = 0; j < 4; ++j) { m[j] = -1e30f; l[j] = 0.f; }

  int kb0 = t0 - (CTX - 1);
  if (kb0 < 0) kb0 = 0;
  kb0 &= ~31;

  for (int kb = kb0; kb <= t0 + 15; kb += 32) {
    // --- QK^T: K B-frags straight from global (L2-resident) ---
    const int key0 = kb + lo, key1 = key0 + 16;
    const int kr0 = key0 < T_SEQ ? key0 : T_SEQ - 1;  // clamp (masked anyway)
    const int kr1 = key1 < T_SEQ ? key1 : T_SEQ - 1;
    const unsigned short* kp0 = Kb + base + (size_t)kr0 * DH + hi * 8;
    const unsigned short* kp1 = Kb + base + (size_t)kr1 * DH + hi * 8;
    bf16x8 k0a = *(const bf16x8*)kp0;
    bf16x8 k0b = *(const bf16x8*)(kp0 + 32);
    bf16x8 k1a = *(const bf16x8*)kp1;
    bf16x8 k1b = *(const bf16x8*)(kp1 + 32);
    f32x4 s0 = __builtin_amdgcn_mfma_f32_16x16x32_bf16(
        qa0, k0a, (f32x4){0.f, 0.f, 0.f, 0.f}, 0, 0, 0);
    s0 = __builtin_amdgcn_mfma_f32_16x16x32_bf16(qa1, k0b, s0, 0, 0, 0);
    f32x4 s1 = __builtin_amdgcn_mfma_f32_16x16x32_bf16(
        qa0, k1a, (f32x4){0.f, 0.f, 0.f, 0.f}, 0, 0, 0);
    s1 = __builtin_amdgcn_mfma_f32_16x16x32_bf16(qa1, k1b, s1, 0, 0, 0);

    // --- band mask + online softmax (rows = 4*hi+j, cols = lo) ---
    float alpha[4];
#pragma unroll
    for (int j = 0; j < 4; ++j) {
      int q = t0 + 4 * hi + j;
      float v0 = ((unsigned)(q - key0) < 256u) ? s0[j] : -1e30f;
      float v1 = ((unsigned)(q - key1) < 256u) ? s1[j] : -1e30f;
      float pm = fmaxf(v0, v1);
      pm = fmaxf(pm, __shfl_xor(pm, 1));
      pm = fmaxf(pm, __shfl_xor(pm, 2));
      pm = fmaxf(pm, __shfl_xor(pm, 4));
      pm = fmaxf(pm, __shfl_xor(pm, 8));
      float mn = fmaxf(m[j], pm);
      alpha[j] = __expf(m[j] - mn);
      m[j] = mn;
      float p0 = __expf(v0 - mn);
      float p1 = __expf(v1 - mn);
      float rs = p0 + p1;
      rs += __shfl_xor(rs, 1);
      rs += __shfl_xor(rs, 2);
      rs += __shfl_xor(rs, 4);
      rs += __shfl_xor(rs, 8);
      l[j] = l[j] * alpha[j] + rs;
      Pb[wid][4 * hi + j][lo] = f2bf(p0);
      Pb[wid][4 * hi + j][lo + 16] = f2bf(p1);
    }
#pragma unroll
    for (int f = 0; f < 4; ++f)
#pragma unroll
      for (int j = 0; j < 4; ++j) O[f][j] *= alpha[j];

    // --- PV: P A-frag from LDS, V^T B-frags from global ---
    bf16x8 pa = *(const bf16x8*)&Pb[wid][lo][hi * 8];
    int vc = kb + hi * 8;
    if (vc > T_SEQ - 8) vc = T_SEQ - 8;  // clamp (P=0 there)
#pragma unroll
    for (int dt = 0; dt < 4; ++dt) {
      bf16x8 vf = *(const bf16x8*)(VT + base + (size_t)(dt * 16 + lo) * T_SEQ + vc);
      O[dt] = __builtin_amdgcn_mfma_f32_16x16x32_bf16(pa, vf, O[dt], 0, 0, 0);
    }
  }

  // --- epilogue: O /= l, write [B,T,C] ---
#pragma unroll
  for (int j = 0; j < 4; ++j) {
    float inv = 1.f / l[j];
    int t = t0 + 4 * hi + j;
    size_t ob = ((size_t)(b * T_SEQ + t)) * C_DIM + h * DH;
#pragma unroll
    for (int dt = 0; dt < 4; ++dt)
      Ab[ob + dt * 16 + lo] = f2bf(O[dt][j] * inv);
  }
}

// ---------------- launch ----------------

extern "C" void kernel_launch(void* const* d_in, const int* in_sizes, int n_in,
                              void* d_out, int out_size, void* d_ws, size_t ws_size,
                              hipStream_t stream) {
  const float* x = (const float*)d_in[0];
  const float* Wa = (const float*)d_in[1];
  const float* ba = (const float*)d_in[2];
  const float* Wp = (const float*)d_in[3];
  const float* bp = (const float*)d_in[4];
  float* out = (float*)d_out;
  char* ws = (char*)d_ws;

  // workspace (72 MB), regions reused over time:
  // [0,16M):  xb (GEMM input)  -> VT (V transposed) after QKV GEMM
  // [16,22M): WaT   [22,24M): WpT
  // [24,40M): Qb    [40,56M): Kb
  // [56,72M): Vb -> Ab (attention output) after v_transpose
  unsigned short* xb  = (unsigned short*)(ws);
  unsigned short* WaT = (unsigned short*)(ws + (16u << 20));
  unsigned short* WpT = (unsigned short*)(ws + (22u << 20));
  unsigned short* Qb  = (unsigned short*)(ws + (24u << 20));
  unsigned short* Kb  = (unsigned short*)(ws + (40u << 20));
  unsigned short* Vb  = (unsigned short*)(ws + (56u << 20));
  unsigned short* VT  = xb;
  unsigned short* Ab  = Vb;

  cvt_f32_bf16<<<2048, 256, 0, stream>>>(x, xb, (B_SZ * T_SEQ * C_DIM) / 8);
  transpose_cvt<<<dim3(96, 32), 256, 0, stream>>>(Wa, WaT, C_DIM, 3 * C_DIM);
  transpose_cvt<<<dim3(32, 32), 256, 0, stream>>>(Wp, WpT, C_DIM, C_DIM);
  gemm_bt<<<dim3(3 * C_DIM / BN, B_SZ * T_SEQ / BM), 256, 0, stream>>>(
      xb, WaT, ba, 3 * C_DIM, C_DIM, 1, nullptr, Qb, Kb, Vb);
  v_transpose<<<(B_SZ * NH * T_SEQ) / 256, 256, 0, stream>>>(Vb, VT);
  attn_mfma<<<(B_SZ * NH * T_SEQ / 16) / 4, 256, 0, stream>>>(Qb, Kb, VT, Ab);
  gemm_bt<<<dim3(C_DIM / BN, B_SZ * T_SEQ / BM), 256, 0, stream>>>(
      Ab, WpT, bp, C_DIM, C_DIM, 0, out, nullptr, nullptr, nullptr);
}

// Round 4
// 193.042 us; speedup vs baseline: 1.1414x; 1.1414x over previous
//
#include <hip/hip_runtime.h>
#include <stdint.h>

#define B_SZ 4
#define T_SEQ 2048
#define C_DIM 1024
#define NH 16
#define DH 64
#define CTX 256

#define AS_G const __attribute__((address_space(1))) void*
#define AS_L __attribute__((address_space(3))) void*

typedef __attribute__((ext_vector_type(8))) short bf16x8;
typedef __attribute__((ext_vector_type(8))) unsigned short u16x8;
typedef __attribute__((ext_vector_type(4))) float f32x4;

__device__ __forceinline__ float bf2f(unsigned short u) {
  unsigned int x = ((unsigned int)u) << 16;
  return __builtin_bit_cast(float, x);
}
__device__ __forceinline__ unsigned short f2bf(float f) {
  unsigned int u = __builtin_bit_cast(unsigned int, f);
  u = (u + 0x7FFFu + ((u >> 16) & 1u)) >> 16;  // RNE; inputs are NaN/inf-free
  return (unsigned short)u;
}

// ---------------- conversion kernels ----------------

__global__ void cvt_f32_bf16(const float* __restrict__ in,
                             unsigned short* __restrict__ out, int n8) {
  int i = blockIdx.x * blockDim.x + threadIdx.x;
  int stride = gridDim.x * blockDim.x;
  for (; i < n8; i += stride) {
    float4 a = ((const float4*)in)[2 * (size_t)i];
    float4 b = ((const float4*)in)[2 * (size_t)i + 1];
    u16x8 r;
    r[0] = f2bf(a.x); r[1] = f2bf(a.y); r[2] = f2bf(a.z); r[3] = f2bf(a.w);
    r[4] = f2bf(b.x); r[5] = f2bf(b.y); r[6] = f2bf(b.z); r[7] = f2bf(b.w);
    *(u16x8*)(out + 8 * (size_t)i) = r;
  }
}

// W[R][CC] f32 -> Wt[CC][R] bf16
__global__ void transpose_cvt(const float* __restrict__ W,
                              unsigned short* __restrict__ Wt, int R, int CC) {
  __shared__ float tile[32][33];
  int ct = blockIdx.x, rt = blockIdx.y;
  int tx = threadIdx.x & 31, ty = threadIdx.x >> 5;
#pragma unroll
  for (int i = 0; i < 4; ++i) {
    int r = ty + i * 8;
    tile[r][tx] = W[(size_t)(rt * 32 + r) * CC + ct * 32 + tx];
  }
  __syncthreads();
#pragma unroll
  for (int i = 0; i < 4; ++i) {
    int r = ty + i * 8;
    Wt[(size_t)(ct * 32 + r) * R + rt * 32 + tx] = f2bf(tile[tx][r]);
  }
}

// V [B,H,T,D] -> VT [B,H,D,T]  (both sides coalesced)
__global__ void v_transpose(const unsigned short* __restrict__ Vb,
                            unsigned short* __restrict__ VT) {
  int idx = blockIdx.x * 256 + threadIdx.x;  // over B*H*T
  int bh = idx >> 11;
  int t = idx & (T_SEQ - 1);
  const unsigned short* src = Vb + ((size_t)bh * T_SEQ + t) * DH;
  unsigned short* dst = VT + (size_t)bh * DH * T_SEQ + t;
#pragma unroll
  for (int d0 = 0; d0 < DH; d0 += 8) {
    u16x8 v = *(const u16x8*)(src + d0);
#pragma unroll
    for (int e = 0; e < 8; ++e) dst[(size_t)(d0 + e) * T_SEQ] = v[e];
  }
}

// ---------------- bf16 MFMA GEMM, B^T layout ----------------
// C[M,N] = A[M,K] * Bt[N,K]^T + bias.  mode 0: fp32 out. mode 1: scatter QKV.
// global_load_lds width=16 into LINEAR LDS dest, with PRE-SWIZZLED global
// source (chunk = (lane&7) ^ (lane>>3)) so the effective LDS layout is
// [row][c ^ (row&7)] — read side applies the same XOR (rule 21, m201).
#define BM 128
#define BN 128
#define BK 64

__global__ __launch_bounds__(256) void gemm_bt(
    const unsigned short* __restrict__ A, const unsigned short* __restrict__ Bt,
    const float* __restrict__ bias, int N, int K, int mode,
    float* __restrict__ outF, unsigned short* __restrict__ Qb,
    unsigned short* __restrict__ Kb, unsigned short* __restrict__ Vb) {
  __shared__ unsigned short As[BM * BK];
  __shared__ unsigned short Bs[BN * BK];
  const int tid = threadIdx.x;
  const int lane = tid & 63;
  const int w = tid >> 6;
  const int wm = w >> 1, wn = w & 1;
  const int m0 = blockIdx.y * BM, n0 = blockIdx.x * BN;

  // staging: lane l of group r8 covers LDS slot row = r8*8 + (l>>3),
  // chunk slot (l&7); its global source chunk is (l&7) ^ (l>>3) so that
  // LDS[row][c] holds global chunk c ^ (row&7).
  const int srow = lane >> 3;
  const int sgch = (lane & 7) ^ srow;

  f32x4 acc[4][4];
#pragma unroll
  for (int mi = 0; mi < 4; ++mi)
#pragma unroll
    for (int ni = 0; ni < 4; ++ni) acc[mi][ni] = (f32x4){0.f, 0.f, 0.f, 0.f};

  for (int k0 = 0; k0 < K; k0 += BK) {
#pragma unroll
    for (int i = 0; i < 4; ++i) {
      int r8 = w * 4 + i;  // 8-row group 0..15
      int row = r8 * 8 + srow;
      __builtin_amdgcn_global_load_lds(
          (AS_G)&A[(size_t)(m0 + row) * K + k0 + sgch * 8],
          (AS_L)((__attribute__((address_space(3))) unsigned short*)As + r8 * 512),
          16, 0, 0);
      __builtin_amdgcn_global_load_lds(
          (AS_G)&Bt[(size_t)(n0 + row) * K + k0 + sgch * 8],
          (AS_L)((__attribute__((address_space(3))) unsigned short*)Bs + r8 * 512),
          16, 0, 0);
    }
    __syncthreads();
#pragma unroll
    for (int ks = 0; ks < 2; ++ks) {
      bf16x8 av[4], bv[4];
      const int colc = (ks << 2) + (lane >> 4);  // 16B chunk index in row
#pragma unroll
      for (int mi = 0; mi < 4; ++mi) {
        int row = wm * 64 + mi * 16 + (lane & 15);
        av[mi] = *(const bf16x8*)&As[row * BK + ((colc ^ (row & 7)) << 3)];
      }
#pragma unroll
      for (int ni = 0; ni < 4; ++ni) {
        int row = wn * 64 + ni * 16 + (lane & 15);
        bv[ni] = *(const bf16x8*)&Bs[row * BK + ((colc ^ (row & 7)) << 3)];
      }
#pragma unroll
      for (int mi = 0; mi < 4; ++mi)
#pragma unroll
        for (int ni = 0; ni < 4; ++ni)
          acc[mi][ni] = __builtin_amdgcn_mfma_f32_16x16x32_bf16(
              av[mi], bv[ni], acc[mi][ni], 0, 0, 0);
    }
    __syncthreads();
  }

  // epilogue: C/D layout col=lane&15, row=(lane>>4)*4+j  (m89/m91 verified)
#pragma unroll
  for (int mi = 0; mi < 4; ++mi) {
#pragma unroll
    for (int ni = 0; ni < 4; ++ni) {
      int gn = n0 + wn * 64 + ni * 16 + (lane & 15);
      float bb = bias[gn];
#pragma unroll
      for (int j = 0; j < 4; ++j) {
        int gm = m0 + wm * 64 + mi * 16 + ((lane >> 4) << 2) + j;
        float v = acc[mi][ni][j] + bb;
        if (mode == 0) {
          outF[(size_t)gm * N + gn] = v;
        } else {
          int sec = gn >> 10, cc = gn & 1023;
          int h = cc >> 6, d = cc & 63;
          int b = gm >> 11, t = gm & 2047;
          size_t dst = (((size_t)(b * NH + h) * T_SEQ) + t) * DH + d;
          float sv = (sec == 0) ? v * 0.125f : v;  // pre-scale Q by 1/sqrt(D)
          unsigned short hv = f2bf(sv);
          if (sec == 0) Qb[dst] = hv;
          else if (sec == 1) Kb[dst] = hv;
          else Vb[dst] = hv;
        }
      }
    }
  }
}

// ---------------- banded causal flash attention (MFMA) ----------------
// one wave per 16-row Q-tile; 4 waves/block; no inter-wave sync needed.
__global__ __launch_bounds__(256) void attn_mfma(
    const unsigned short* __restrict__ Qb,  // [B,H,T,D] (pre-scaled)
    const unsigned short* __restrict__ Kb,  // [B,H,T,D]
    const unsigned short* __restrict__ VT,  // [B,H,D,T]
    unsigned short* __restrict__ Ab) {      // [B,T,C]
  __shared__ unsigned short Pb[4][16][40];  // padded: row stride 80B
  const int wid = threadIdx.x >> 6, lane = threadIdx.x & 63;
  const int lo = lane & 15, hi = lane >> 4;
  const int bh = blockIdx.x >> 5;                       // 32 blocks per (b,h)
  const int t0 = ((blockIdx.x & 31) * 4 + wid) * 16;    // q-tile start
  const int b = bh >> 4, h = bh & 15;
  const size_t base = (size_t)bh * (T_SEQ * DH);

  // Q A-frags (row = lo, k = hi*8+e)
  const unsigned short* qp = Qb + base + (size_t)(t0 + lo) * DH + hi * 8;
  bf16x8 qa0 = *(const bf16x8*)qp;
  bf16x8 qa1 = *(const bf16x8*)(qp + 32);

  f32x4 O[4];
#pragma unroll
  for (int f = 0; f < 4; ++f) O[f] = (f32x4){0.f, 0.f, 0.f, 0.f};
  float m[4], l[4];
#pragma unroll
  for (int j = 0; j < 4; ++j) { m[j] = -1e30f; l[j] = 0.f; }

  int kb0 = t0 - (CTX - 1);
  if (kb0 < 0) kb0 = 0;
  kb0 &= ~31;

  for (int kb = kb0; kb <= t0 + 15; kb += 32) {
    // --- QK^T: K B-frags straight from global (L2-resident) ---
    const int key0 = kb + lo, key1 = key0 + 16;
    const int kr0 = key0 < T_SEQ ? key0 : T_SEQ - 1;  // clamp (masked anyway)
    const int kr1 = key1 < T_SEQ ? key1 : T_SEQ - 1;
    const unsigned short* kp0 = Kb + base + (size_t)kr0 * DH + hi * 8;
    const unsigned short* kp1 = Kb + base + (size_t)kr1 * DH + hi * 8;
    bf16x8 k0a = *(const bf16x8*)kp0;
    bf16x8 k0b = *(const bf16x8*)(kp0 + 32);
    bf16x8 k1a = *(const bf16x8*)kp1;
    bf16x8 k1b = *(const bf16x8*)(kp1 + 32);
    f32x4 s0 = __builtin_amdgcn_mfma_f32_16x16x32_bf16(
        qa0, k0a, (f32x4){0.f, 0.f, 0.f, 0.f}, 0, 0, 0);
    s0 = __builtin_amdgcn_mfma_f32_16x16x32_bf16(qa1, k0b, s0, 0, 0, 0);
    f32x4 s1 = __builtin_amdgcn_mfma_f32_16x16x32_bf16(
        qa0, k1a, (f32x4){0.f, 0.f, 0.f, 0.f}, 0, 0, 0);
    s1 = __builtin_amdgcn_mfma_f32_16x16x32_bf16(qa1, k1b, s1, 0, 0, 0);

    // --- band mask + online softmax (rows = 4*hi+j, cols = lo) ---
    float alpha[4];
#pragma unroll
    for (int j = 0; j < 4; ++j) {
      int q = t0 + 4 * hi + j;
      float v0 = ((unsigned)(q - key0) < 256u) ? s0[j] : -1e30f;
      float v1 = ((unsigned)(q - key1) < 256u) ? s1[j] : -1e30f;
      float pm = fmaxf(v0, v1);
      pm = fmaxf(pm, __shfl_xor(pm, 1));
      pm = fmaxf(pm, __shfl_xor(pm, 2));
      pm = fmaxf(pm, __shfl_xor(pm, 4));
      pm = fmaxf(pm, __shfl_xor(pm, 8));
      float mn = fmaxf(m[j], pm);
      alpha[j] = __expf(m[j] - mn);
      m[j] = mn;
      float p0 = __expf(v0 - mn);
      float p1 = __expf(v1 - mn);
      float rs = p0 + p1;
      rs += __shfl_xor(rs, 1);
      rs += __shfl_xor(rs, 2);
      rs += __shfl_xor(rs, 4);
      rs += __shfl_xor(rs, 8);
      l[j] = l[j] * alpha[j] + rs;
      Pb[wid][4 * hi + j][lo] = f2bf(p0);
      Pb[wid][4 * hi + j][lo + 16] = f2bf(p1);
    }
#pragma unroll
    for (int f = 0; f < 4; ++f)
#pragma unroll
      for (int j = 0; j < 4; ++j) O[f][j] *= alpha[j];

    // --- PV: P A-frag from LDS, V^T B-frags from global ---
    bf16x8 pa = *(const bf16x8*)&Pb[wid][lo][hi * 8];
    int vc = kb + hi * 8;
    if (vc > T_SEQ - 8) vc = T_SEQ - 8;  // clamp (P=0 there)
#pragma unroll
    for (int dt = 0; dt < 4; ++dt) {
      bf16x8 vf = *(const bf16x8*)(VT + base + (size_t)(dt * 16 + lo) * T_SEQ + vc);
      O[dt] = __builtin_amdgcn_mfma_f32_16x16x32_bf16(pa, vf, O[dt], 0, 0, 0);
    }
  }

  // --- epilogue: O /= l, write [B,T,C] ---
#pragma unroll
  for (int j = 0; j < 4; ++j) {
    float inv = 1.f / l[j];
    int t = t0 + 4 * hi + j;
    size_t ob = ((size_t)(b * T_SEQ + t)) * C_DIM + h * DH;
#pragma unroll
    for (int dt = 0; dt < 4; ++dt)
      Ab[ob + dt * 16 + lo] = f2bf(O[dt][j] * inv);
  }
}

// ---------------- launch ----------------

extern "C" void kernel_launch(void* const* d_in, const int* in_sizes, int n_in,
                              void* d_out, int out_size, void* d_ws, size_t ws_size,
                              hipStream_t stream) {
  const float* x = (const float*)d_in[0];
  const float* Wa = (const float*)d_in[1];
  const float* ba = (const float*)d_in[2];
  const float* Wp = (const float*)d_in[3];
  const float* bp = (const float*)d_in[4];
  float* out = (float*)d_out;
  char* ws = (char*)d_ws;

  // workspace (72 MB), regions reused over time:
  // [0,16M):  xb (GEMM input)  -> VT (V transposed) after QKV GEMM
  // [16,22M): WaT   [22,24M): WpT
  // [24,40M): Qb    [40,56M): Kb
  // [56,72M): Vb -> Ab (attention output) after v_transpose
  unsigned short* xb  = (unsigned short*)(ws);
  unsigned short* WaT = (unsigned short*)(ws + (16u << 20));
  unsigned short* WpT = (unsigned short*)(ws + (22u << 20));
  unsigned short* Qb  = (unsigned short*)(ws + (24u << 20));
  unsigned short* Kb  = (unsigned short*)(ws + (40u << 20));
  unsigned short* Vb  = (unsigned short*)(ws + (56u << 20));
  unsigned short* VT  = xb;
  unsigned short* Ab  = Vb;

  cvt_f32_bf16<<<2048, 256, 0, stream>>>(x, xb, (B_SZ * T_SEQ * C_DIM) / 8);
  transpose_cvt<<<dim3(96, 32), 256, 0, stream>>>(Wa, WaT, C_DIM, 3 * C_DIM);
  transpose_cvt<<<dim3(32, 32), 256, 0, stream>>>(Wp, WpT, C_DIM, C_DIM);
  gemm_bt<<<dim3(3 * C_DIM / BN, B_SZ * T_SEQ / BM), 256, 0, stream>>>(
      xb, WaT, ba, 3 * C_DIM, C_DIM, 1, nullptr, Qb, Kb, Vb);
  v_transpose<<<(B_SZ * NH * T_SEQ) / 256, 256, 0, stream>>>(Vb, VT);
  attn_mfma<<<(B_SZ * NH * T_SEQ / 16) / 4, 256, 0, stream>>>(Qb, Kb, VT, Ab);
  gemm_bt<<<dim3(C_DIM / BN, B_SZ * T_SEQ / BM), 256, 0, stream>>>(
      Ab, WpT, bp, C_DIM, C_DIM, 0, out, nullptr, nullptr, nullptr);
}

// Round 5
// 179.307 us; speedup vs baseline: 1.2288x; 1.0766x over previous
//
#include <hip/hip_runtime.h>
#include <stdint.h>

#define B_SZ 4
#define T_SEQ 2048
#define C_DIM 1024
#define NH 16
#define DH 64
#define CTX 256

#define AS_G const __attribute__((address_space(1))) void*
#define AS_L __attribute__((address_space(3))) void*

typedef __attribute__((ext_vector_type(8))) short bf16x8;
typedef __attribute__((ext_vector_type(8))) unsigned short u16x8;
typedef __attribute__((ext_vector_type(4))) unsigned short u16x4;
typedef __attribute__((ext_vector_type(4))) float f32x4;

__device__ __forceinline__ float bf2f(unsigned short u) {
  unsigned int x = ((unsigned int)u) << 16;
  return __builtin_bit_cast(float, x);
}
__device__ __forceinline__ unsigned short f2bf(float f) {
  unsigned int u = __builtin_bit_cast(unsigned int, f);
  u = (u + 0x7FFFu + ((u >> 16) & 1u)) >> 16;  // RNE; inputs are NaN/inf-free
  return (unsigned short)u;
}

// ---------------- conversion kernels ----------------

__global__ void cvt_f32_bf16(const float* __restrict__ in,
                             unsigned short* __restrict__ out, int n8) {
  int i = blockIdx.x * blockDim.x + threadIdx.x;
  int stride = gridDim.x * blockDim.x;
  for (; i < n8; i += stride) {
    float4 a = ((const float4*)in)[2 * (size_t)i];
    float4 b = ((const float4*)in)[2 * (size_t)i + 1];
    u16x8 r;
    r[0] = f2bf(a.x); r[1] = f2bf(a.y); r[2] = f2bf(a.z); r[3] = f2bf(a.w);
    r[4] = f2bf(b.x); r[5] = f2bf(b.y); r[6] = f2bf(b.z); r[7] = f2bf(b.w);
    *(u16x8*)(out + 8 * (size_t)i) = r;
  }
}

// W[R][CC] f32 -> Wt[CC][R] bf16
__global__ void transpose_cvt(const float* __restrict__ W,
                              unsigned short* __restrict__ Wt, int R, int CC) {
  __shared__ float tile[32][33];
  int ct = blockIdx.x, rt = blockIdx.y;
  int tx = threadIdx.x & 31, ty = threadIdx.x >> 5;
#pragma unroll
  for (int i = 0; i < 4; ++i) {
    int r = ty + i * 8;
    tile[r][tx] = W[(size_t)(rt * 32 + r) * CC + ct * 32 + tx];
  }
  __syncthreads();
#pragma unroll
  for (int i = 0; i < 4; ++i) {
    int r = ty + i * 8;
    Wt[(size_t)(ct * 32 + r) * R + rt * 32 + tx] = f2bf(tile[tx][r]);
  }
}

// ---------------- bf16 MFMA GEMM, B^T layout ----------------
// C[M,N] = A[M,K] * Bt[N,K]^T + bias.  mode 0: fp32 out. mode 1: scatter QKV
// (Q pre-scaled by 1/8, V written directly transposed to [B,H,D,T]).
// global_load_lds width=16 into LINEAR LDS dest, with PRE-SWIZZLED global
// source (chunk = (lane&7) ^ (lane>>3)); read side applies the same XOR.
#define BM 128
#define BN 128
#define BK 64

__global__ __launch_bounds__(256) void gemm_bt(
    const unsigned short* __restrict__ A, const unsigned short* __restrict__ Bt,
    const float* __restrict__ bias, int N, int K, int mode,
    float* __restrict__ outF, unsigned short* __restrict__ Qb,
    unsigned short* __restrict__ Kb, unsigned short* __restrict__ VTb) {
  __shared__ unsigned short As[BM * BK];
  __shared__ unsigned short Bs[BN * BK];
  const int tid = threadIdx.x;
  const int lane = tid & 63;
  const int w = tid >> 6;
  const int wm = w >> 1, wn = w & 1;
  const int m0 = blockIdx.y * BM, n0 = blockIdx.x * BN;

  const int srow = lane >> 3;
  const int sgch = (lane & 7) ^ srow;

  f32x4 acc[4][4];
#pragma unroll
  for (int mi = 0; mi < 4; ++mi)
#pragma unroll
    for (int ni = 0; ni < 4; ++ni) acc[mi][ni] = (f32x4){0.f, 0.f, 0.f, 0.f};

  for (int k0 = 0; k0 < K; k0 += BK) {
#pragma unroll
    for (int i = 0; i < 4; ++i) {
      int r8 = w * 4 + i;  // 8-row group 0..15
      int row = r8 * 8 + srow;
      __builtin_amdgcn_global_load_lds(
          (AS_G)&A[(size_t)(m0 + row) * K + k0 + sgch * 8],
          (AS_L)((__attribute__((address_space(3))) unsigned short*)As + r8 * 512),
          16, 0, 0);
      __builtin_amdgcn_global_load_lds(
          (AS_G)&Bt[(size_t)(n0 + row) * K + k0 + sgch * 8],
          (AS_L)((__attribute__((address_space(3))) unsigned short*)Bs + r8 * 512),
          16, 0, 0);
    }
    __syncthreads();
#pragma unroll
    for (int ks = 0; ks < 2; ++ks) {
      bf16x8 av[4], bv[4];
      const int colc = (ks << 2) + (lane >> 4);  // 16B chunk index in row
#pragma unroll
      for (int mi = 0; mi < 4; ++mi) {
        int row = wm * 64 + mi * 16 + (lane & 15);
        av[mi] = *(const bf16x8*)&As[row * BK + ((colc ^ (row & 7)) << 3)];
      }
#pragma unroll
      for (int ni = 0; ni < 4; ++ni) {
        int row = wn * 64 + ni * 16 + (lane & 15);
        bv[ni] = *(const bf16x8*)&Bs[row * BK + ((colc ^ (row & 7)) << 3)];
      }
#pragma unroll
      for (int mi = 0; mi < 4; ++mi)
#pragma unroll
        for (int ni = 0; ni < 4; ++ni)
          acc[mi][ni] = __builtin_amdgcn_mfma_f32_16x16x32_bf16(
              av[mi], bv[ni], acc[mi][ni], 0, 0, 0);
    }
    __syncthreads();
  }

  // epilogue: C/D layout col=lane&15, row=(lane>>4)*4+j  (m89/m91 verified)
#pragma unroll
  for (int mi = 0; mi < 4; ++mi) {
#pragma unroll
    for (int ni = 0; ni < 4; ++ni) {
      int gn = n0 + wn * 64 + ni * 16 + (lane & 15);
      float bb = bias[gn];
      int gmb = m0 + wm * 64 + mi * 16 + ((lane >> 4) << 2);  // j=0 row
      if (mode == 0) {
#pragma unroll
        for (int j = 0; j < 4; ++j)
          outF[(size_t)(gmb + j) * N + gn] = acc[mi][ni][j] + bb;
      } else {
        int sec = gn >> 10, cc = gn & 1023;
        int h = cc >> 6, d = cc & 63;
        int b = gmb >> 11, t = gmb & 2047;  // 4-aligned, no b crossing
        if (sec == 2) {
          // V: write transposed [B,H,D,T]; 4 consecutive t -> one 8B store
          u16x4 pk;
#pragma unroll
          for (int j = 0; j < 4; ++j) pk[j] = f2bf(acc[mi][ni][j] + bb);
          *(u16x4*)&VTb[((size_t)(b * NH + h) * DH + d) * T_SEQ + t] = pk;
        } else {
          size_t dst = (((size_t)(b * NH + h) * T_SEQ) + t) * DH + d;
          float sc = (sec == 0) ? 0.125f : 1.0f;  // pre-scale Q by 1/sqrt(D)
          unsigned short* P = (sec == 0) ? Qb : Kb;
#pragma unroll
          for (int j = 0; j < 4; ++j)
            P[dst + (size_t)j * DH] = f2bf((acc[mi][ni][j] + bb) * sc);
        }
      }
    }
  }
}

// ---------------- banded causal flash attention (MFMA, swapped operands) ---
// S^T = mfma(K,Q): each lane owns ONE q-row (col=lane&15) -> softmax is
// in-lane over 8 regs + 2 shuffles (xor16/32). PV: O^T = mfma(V^T, P^T).
__global__ __launch_bounds__(256) void attn_mfma(
    const unsigned short* __restrict__ Qb,  // [B,H,T,D] (pre-scaled)
    const unsigned short* __restrict__ Kb,  // [B,H,T,D]
    const unsigned short* __restrict__ VT,  // [B,H,D,T]
    unsigned short* __restrict__ Ab) {      // [B,T,C]
  __shared__ unsigned short Pb[4][16][40];  // P^T: [q-row][key], row stride 80B
  const int wid = threadIdx.x >> 6, lane = threadIdx.x & 63;
  const int lo = lane & 15, hi = lane >> 4;
  const int bh = blockIdx.x >> 5;                     // 32 blocks per (b,h)
  const int t0 = ((blockIdx.x & 31) * 4 + wid) * 16;  // q-tile start
  const int b = bh >> 4, h = bh & 15;
  const size_t base = (size_t)bh * (T_SEQ * DH);
  const int tq = t0 + lo;  // this lane's q-row

  // Q B-frag: row = lo (q-row), k = hi*8+e
  const unsigned short* qp = Qb + base + (size_t)tq * DH + hi * 8;
  bf16x8 qa0 = *(const bf16x8*)qp;
  bf16x8 qa1 = *(const bf16x8*)(qp + 32);

  f32x4 O[4];
#pragma unroll
  for (int f = 0; f < 4; ++f) O[f] = (f32x4){0.f, 0.f, 0.f, 0.f};
  float m = -1e30f, l = 0.f;

  int kb0 = t0 - (CTX - 1);
  if (kb0 < 0) kb0 = 0;
  kb0 &= ~31;

  for (int kb = kb0; kb <= t0 + 15; kb += 32) {
    // K A-frags: rows = keys kb+lo / kb+16+lo (always in-range, see bounds)
    const unsigned short* kp0 = Kb + base + (size_t)(kb + lo) * DH + hi * 8;
    const unsigned short* kp1 = kp0 + 16 * DH;
    bf16x8 k0a = *(const bf16x8*)kp0;
    bf16x8 k0b = *(const bf16x8*)(kp0 + 32);
    bf16x8 k1a = *(const bf16x8*)kp1;
    bf16x8 k1b = *(const bf16x8*)(kp1 + 32);
    // S^T[key][q]: col=lo=q, row=4hi+j=key-kb (s0), +16 (s1)
    f32x4 s0 = __builtin_amdgcn_mfma_f32_16x16x32_bf16(
        k0a, qa0, (f32x4){0.f, 0.f, 0.f, 0.f}, 0, 0, 0);
    s0 = __builtin_amdgcn_mfma_f32_16x16x32_bf16(k0b, qa1, s0, 0, 0, 0);
    f32x4 s1 = __builtin_amdgcn_mfma_f32_16x16x32_bf16(
        k1a, qa0, (f32x4){0.f, 0.f, 0.f, 0.f}, 0, 0, 0);
    s1 = __builtin_amdgcn_mfma_f32_16x16x32_bf16(k1b, qa1, s1, 0, 0, 0);

    // band mask (skip for interior full-valid blocks; kb,t0 wave-uniform)
    float v[8];
    const bool full = (kb >= t0 - 240) && (kb + 31 <= t0);
    if (full) {
#pragma unroll
      for (int j = 0; j < 4; ++j) { v[j] = s0[j]; v[4 + j] = s1[j]; }
    } else {
#pragma unroll
      for (int j = 0; j < 4; ++j) {
        int key = kb + 4 * hi + j;
        v[j] = ((unsigned)(tq - key) < 256u) ? s0[j] : -1e30f;
        v[4 + j] = ((unsigned)(tq - key - 16) < 256u) ? s1[j] : -1e30f;
      }
    }

    // in-lane row max + 2 shuffles (lanes lo,lo+16,lo+32,lo+48 share q-row)
    float pmax = fmaxf(fmaxf(fmaxf(v[0], v[1]), fmaxf(v[2], v[3])),
                       fmaxf(fmaxf(v[4], v[5]), fmaxf(v[6], v[7])));
    pmax = fmaxf(pmax, __shfl_xor(pmax, 16));
    pmax = fmaxf(pmax, __shfl_xor(pmax, 32));
    float mn = fmaxf(m, pmax);
    float alpha = __expf(m - mn);
    m = mn;
    float p[8];
    float rs = 0.f;
#pragma unroll
    for (int i = 0; i < 8; ++i) p[i] = __expf(v[i] - mn);
    rs = ((p[0] + p[1]) + (p[2] + p[3])) + ((p[4] + p[5]) + (p[6] + p[7]));
    rs += __shfl_xor(rs, 16);
    rs += __shfl_xor(rs, 32);
    l = l * alpha + rs;

    // P^T bounce through LDS: lane holds keys {4hi+j, 16+4hi+j} of row lo
    u16x4 w0, w1;
#pragma unroll
    for (int j = 0; j < 4; ++j) { w0[j] = f2bf(p[j]); w1[j] = f2bf(p[4 + j]); }
    *(u16x4*)&Pb[wid][lo][4 * hi] = w0;
    *(u16x4*)&Pb[wid][lo][16 + 4 * hi] = w1;

#pragma unroll
    for (int f = 0; f < 4; ++f) O[f] *= alpha;

    // PV: A = V^T (row=d=dt*16+lo, k=keys kb+hi*8+e), B = P^T (row=q=lo)
    bf16x8 pa = *(const bf16x8*)&Pb[wid][lo][hi * 8];
    const unsigned short* vp = VT + base + (size_t)lo * T_SEQ + kb + hi * 8;
#pragma unroll
    for (int dt = 0; dt < 4; ++dt) {
      bf16x8 vf = *(const bf16x8*)(vp + (size_t)(dt * 16) * T_SEQ);
      O[dt] = __builtin_amdgcn_mfma_f32_16x16x32_bf16(vf, pa, O[dt], 0, 0, 0);
    }
  }

  // epilogue: O^T[d][q]: lane q=tq holds d = dt*16+4hi+j (j contiguous)
  float inv = 1.f / l;
  size_t ob = ((size_t)(b * T_SEQ + tq)) * C_DIM + h * DH + 4 * hi;
#pragma unroll
  for (int dt = 0; dt < 4; ++dt) {
    u16x4 o;
#pragma unroll
    for (int j = 0; j < 4; ++j) o[j] = f2bf(O[dt][j] * inv);
    *(u16x4*)&Ab[ob + dt * 16] = o;
  }
}

// ---------------- launch ----------------

extern "C" void kernel_launch(void* const* d_in, const int* in_sizes, int n_in,
                              void* d_out, int out_size, void* d_ws, size_t ws_size,
                              hipStream_t stream) {
  const float* x = (const float*)d_in[0];
  const float* Wa = (const float*)d_in[1];
  const float* ba = (const float*)d_in[2];
  const float* Wp = (const float*)d_in[3];
  const float* bp = (const float*)d_in[4];
  float* out = (float*)d_out;
  char* ws = (char*)d_ws;

  // workspace (72 MB):
  // [0,16M):  xb (QKV-GEMM input) -> Ab (attention output) after QKV GEMM
  // [16,22M): WaT   [22,24M): WpT
  // [24,40M): Qb    [40,56M): Kb    [56,72M): VT ([B,H,D,T], written by GEMM)
  unsigned short* xb  = (unsigned short*)(ws);
  unsigned short* WaT = (unsigned short*)(ws + (16u << 20));
  unsigned short* WpT = (unsigned short*)(ws + (22u << 20));
  unsigned short* Qb  = (unsigned short*)(ws + (24u << 20));
  unsigned short* Kb  = (unsigned short*)(ws + (40u << 20));
  unsigned short* VT  = (unsigned short*)(ws + (56u << 20));
  unsigned short* Ab  = xb;

  cvt_f32_bf16<<<2048, 256, 0, stream>>>(x, xb, (B_SZ * T_SEQ * C_DIM) / 8);
  transpose_cvt<<<dim3(96, 32), 256, 0, stream>>>(Wa, WaT, C_DIM, 3 * C_DIM);
  transpose_cvt<<<dim3(32, 32), 256, 0, stream>>>(Wp, WpT, C_DIM, C_DIM);
  gemm_bt<<<dim3(3 * C_DIM / BN, B_SZ * T_SEQ / BM), 256, 0, stream>>>(
      xb, WaT, ba, 3 * C_DIM, C_DIM, 1, nullptr, Qb, Kb, VT);
  attn_mfma<<<(B_SZ * NH * T_SEQ / 16) / 4, 256, 0, stream>>>(Qb, Kb, VT, Ab);
  gemm_bt<<<dim3(C_DIM / BN, B_SZ * T_SEQ / BM), 256, 0, stream>>>(
      Ab, WpT, bp, C_DIM, C_DIM, 0, out, nullptr, nullptr, nullptr);
}